// Round 14
// baseline (196.234 us; speedup 1.0000x reference)
//
#include <hip/hip_runtime.h>
#include <hip/hip_bf16.h>

using bf16 = __hip_bfloat16;
typedef unsigned short u16;
typedef unsigned int   u32;
typedef __attribute__((ext_vector_type(8))) short short8;   // 8 bf16 = 4 VGPRs (MFMA A/B frag)
typedef __attribute__((ext_vector_type(4))) float f32x4;    // MFMA C/D frag

#define B_N 2
#define CCH 128
#define HH 192
#define WW 192
#define HWS (HH*WW)          // 36864
#define NBLKS 576            // 24*24 halo blocks per batch
#define EPSV 1e-5f
#define LDW 136              // LDS row stride (u16) for MFMA tiles

__device__ __forceinline__ float b2f(bf16 v){ return __bfloat162float(v); }
__device__ __forceinline__ bf16  f2b(float v){ return __float2bfloat16(v); }
__device__ __forceinline__ u32 pck(float a, float b){
    bf16 x = f2b(a), y = f2b(b);
    return (u32)*(u16*)&x | ((u32)*(u16*)&y << 16);
}

// ---------------------------------------------------------------------------
// Weight prep -> bf16 blob, all [co][ci]:
// [0,16K) W1 | [16K,32K) Wq*qscale | [32K,48K) Wk | [48K,64K) Wv | [64K,80K) Wo
// [80K,224K) W3 [tap][co][ci] | [229376,230400) rel_h (992+32 zero pad)
// [230400,231424) rel_w (992+32 zero pad)
// ---------------------------------------------------------------------------
__global__ __launch_bounds__(256) void prep_w(
    const float* __restrict__ w1, const float* __restrict__ to_q,
    const float* __restrict__ to_kv, const float* __restrict__ to_ow,
    const float* __restrict__ w3, const float* __restrict__ relh,
    const float* __restrict__ relw, bf16* __restrict__ wb)
{
    int i = blockIdx.x*256 + threadIdx.x;      // < 231424 (904*256)
    float v;
    if (i < 16384){       int co=(i>>7)&127, ci=i&127;      v = w1[ci*128+co]; }
    else if (i < 32768){  int r=i-16384; int co=r>>7, ci=r&127; v = to_q[ci*128+co]*0.17677669529663687f; }
    else if (i < 49152){  int r=i-32768; int co=r>>7, ci=r&127; v = to_kv[ci*256+co]; }
    else if (i < 65536){  int r=i-49152; int co=r>>7, ci=r&127; v = to_kv[ci*256+128+co]; }
    else if (i < 81920){  int r=i-65536; int co=r>>7, ci=r&127; v = to_ow[ci*128+co]; }
    else if (i < 229376){ int r=i-81920; int tap=r>>14, co=(r>>7)&127, ci=r&127; int a=tap/3, b=tap-a*3;
                          v = w3[((size_t)(ci*128+co)*3+a)*3+b]; }
    else if (i < 230400){ int j=i-229376; v = (j < 992) ? relh[j] : 0.f; }
    else                { int j=i-230400; v = (j < 992) ? relw[j] : 0.f; }
    wb[i] = f2b(v);
}

// ---------------------------------------------------------------------------
// conv1: NCHW f32 input -> fused LDS transpose -> MFMA -> BN1+ReLU -> [P][128]
// ---------------------------------------------------------------------------
__global__ __launch_bounds__(256) void conv1_mfma(
    const float* __restrict__ x, const bf16* __restrict__ Wp,
    bf16* __restrict__ outp,
    const float* __restrict__ bn_g, const float* __restrict__ bn_b,
    const float* __restrict__ bn_m, const float* __restrict__ bn_v)
{
    __shared__ float tF[128*68];               // 34816 B; sW overlays after pack
    __shared__ u16   sX[64*LDW];               // 17408 B
    u16* sW = (u16*)tF;
    const int tid  = threadIdx.x;
    const int pix0 = blockIdx.x * 64;
    const int n    = pix0 / HWS;
    const int hwb  = pix0 - n*HWS;
    const int lane = tid & 63;
    const int ln = lane & 15, g = lane >> 4;
    const int cow = (tid >> 6) * 32;

    #pragma unroll
    for (int r = 0; r < 8; ++r){
        int e = tid + r*256;                   // 0..2047
        int ci = e >> 4, p4 = e & 15;
        *(float4*)&tF[ci*68 + p4*4] =
            *(const float4*)&x[(size_t)(n*CCH + ci)*HWS + hwb + p4*4];
    }
    __syncthreads();
    {
        const int pix = tid & 63, cq = tid >> 6;
        u32 pkt[16];
        #pragma unroll
        for (int c = 0; c < 16; ++c){
            int ci = cq*32 + c*2;
            pkt[c] = pck(tF[ci*68 + pix], tF[(ci+1)*68 + pix]);
        }
        u32* dst = (u32*)&sX[pix*LDW + cq*32];
        #pragma unroll
        for (int c = 0; c < 16; ++c) dst[c] = pkt[c];
    }
    __syncthreads();
    #pragma unroll
    for (int r = 0; r < 8; ++r){
        int e = tid + r*256; int row = e>>4, grp = e&15;
        *(uint4*)&sW[row*LDW + grp*8] = *(const uint4*)&Wp[row*128 + grp*8];
    }
    __syncthreads();

    f32x4 acc[4][2];
    #pragma unroll
    for (int mi=0;mi<4;mi++)
        #pragma unroll
        for (int ni=0;ni<2;ni++) acc[mi][ni] = (f32x4){0.f,0.f,0.f,0.f};
    #pragma unroll
    for (int kk = 0; kk < 4; ++kk){
        short8 fa[4], fb[2];
        #pragma unroll
        for (int mi=0;mi<4;mi++)
            fa[mi] = *(const short8*)&sX[(mi*16+ln)*LDW + kk*32 + g*8];
        #pragma unroll
        for (int ni=0;ni<2;ni++)
            fb[ni] = *(const short8*)&sW[(cow+ni*16+ln)*LDW + kk*32 + g*8];
        #pragma unroll
        for (int mi=0;mi<4;mi++)
            #pragma unroll
            for (int ni=0;ni<2;ni++)
                acc[mi][ni] = __builtin_amdgcn_mfma_f32_16x16x32_bf16(fa[mi], fb[ni], acc[mi][ni], 0, 0, 0);
    }
    float sc[2], bb[2];
    #pragma unroll
    for (int ni=0;ni<2;ni++){
        int co = cow + ni*16 + ln;
        float sg = bn_g[co]*rsqrtf(bn_v[co]+EPSV);
        sc[ni] = sg; bb[ni] = bn_b[co] - bn_m[co]*sg;
    }
    #pragma unroll
    for (int mi=0;mi<4;mi++)
        #pragma unroll
        for (int ni=0;ni<2;ni++)
            #pragma unroll
            for (int j=0;j<4;j++){
                int pix = pix0 + mi*16 + g*4 + j;
                int co  = cow + ni*16 + ln;
                float v = fmaxf(acc[mi][ni][j]*sc[ni] + bb[ni], 0.f);
                outp[(size_t)pix*CCH + co] = f2b(v);
            }
}

// ---------------------------------------------------------------------------
// MFMA channel GEMM (verified r5-r13). blockIdx.y selects a 128-co slab.
// TRANS_Y2: slab y==2 writes output transposed NCHW to outp2 (for V).
// ---------------------------------------------------------------------------
template<bool DO_BIAS, bool DO_RELU, bool TRANS_Y2>
__global__ __launch_bounds__(256) void gemm_mfma(
    const bf16* __restrict__ inp, const bf16* __restrict__ Wp,
    bf16* __restrict__ outp, bf16* __restrict__ outp2, int cstride, int choff,
    const float* __restrict__ bias)
{
    Wp    += (size_t)blockIdx.y * 16384;
    choff += blockIdx.y * 128;
    __shared__ u16 sW[128*LDW];
    __shared__ u16 sX[64*LDW];
    const int tid  = threadIdx.x;
    const int pix0 = blockIdx.x * 64;
    const int lane = tid & 63;
    const int ln = lane & 15, g = lane >> 4;
    const int cow = (tid >> 6) * 32;

    #pragma unroll
    for (int r = 0; r < 8; ++r){
        int e = tid + r*256; int row = e>>4, grp = e&15;
        *(uint4*)&sW[row*LDW + grp*8] = *(const uint4*)&Wp[row*128 + grp*8];
    }
    #pragma unroll
    for (int r = 0; r < 4; ++r){
        int e = tid + r*256; int row = e>>4, grp = e&15;
        *(uint4*)&sX[row*LDW + grp*8] = *(const uint4*)&inp[(size_t)(pix0+row)*CCH + grp*8];
    }
    __syncthreads();

    f32x4 acc[4][2];
    #pragma unroll
    for (int mi=0;mi<4;mi++)
        #pragma unroll
        for (int ni=0;ni<2;ni++) acc[mi][ni] = (f32x4){0.f,0.f,0.f,0.f};

    #pragma unroll
    for (int kk = 0; kk < 4; ++kk){
        short8 fa[4], fb[2];
        #pragma unroll
        for (int mi=0;mi<4;mi++)
            fa[mi] = *(const short8*)&sX[(mi*16+ln)*LDW + kk*32 + g*8];
        #pragma unroll
        for (int ni=0;ni<2;ni++)
            fb[ni] = *(const short8*)&sW[(cow+ni*16+ln)*LDW + kk*32 + g*8];
        #pragma unroll
        for (int mi=0;mi<4;mi++)
            #pragma unroll
            for (int ni=0;ni<2;ni++)
                acc[mi][ni] = __builtin_amdgcn_mfma_f32_16x16x32_bf16(fa[mi], fb[ni], acc[mi][ni], 0, 0, 0);
    }

    if (TRANS_Y2 && blockIdx.y == 2){
        __syncthreads();
        u16* tile = sX;
        #pragma unroll
        for (int mi=0;mi<4;mi++)
            #pragma unroll
            for (int ni=0;ni<2;ni++){
                int co   = cow + ni*16 + ln;
                int pixl = mi*16 + g*4;
                *(u32*)&tile[co*68 + pixl]     = pck(acc[mi][ni][0], acc[mi][ni][1]);
                *(u32*)&tile[co*68 + pixl + 2] = pck(acc[mi][ni][2], acc[mi][ni][3]);
            }
        __syncthreads();
        const int co2 = tid >> 1, hf = tid & 1;
        const int n2 = pix0 / HWS, hwb2 = pix0 - n2*HWS;
        u16* gdst = (u16*)outp2 + (size_t)(n2*CCH + co2)*HWS + hwb2 + hf*32;
        const u16* src = &tile[co2*68 + hf*32];
        #pragma unroll
        for (int k=0;k<8;k++)
            *(uint2*)&gdst[k*4] = *(const uint2*)&src[k*4];
        return;
    }

    float bb[2];
    #pragma unroll
    for (int ni=0;ni<2;ni++){
        int co = cow + ni*16 + ln;
        bb[ni] = DO_BIAS ? bias[co] : 0.f;
    }
    #pragma unroll
    for (int mi=0;mi<4;mi++)
        #pragma unroll
        for (int ni=0;ni<2;ni++)
            #pragma unroll
            for (int j=0;j<4;j++){
                int pix = pix0 + mi*16 + g*4 + j;
                int co  = cow + ni*16 + ln;
                float v = acc[mi][ni][j] + bb[ni];
                if (DO_RELU) v = fmaxf(v, 0.f);
                outp[(size_t)pix*cstride + choff + co] = f2b(v);
            }
}

// ---------------------------------------------------------------------------
// conv3 v4 = r13 structure + two fixes:
//  (a) __launch_bounds__(256,4): VGPR cap 128 — r13's compiler-chosen 64-VGPR
//      cap spilled ~30 regs -> 252 MB scratch writes (measured). ~90 regs fit.
//  (b) co-half split via bid>=1152 (not bid&1): paired blocks i and i+1152
//      land on the SAME XCD (1152%8==0) -> the shared X strip is an L2 hit.
// W staged in LDS per tap with T14 reg-prefetch; X halo strip serves 3 column
// taps (r12/r13-verified). LDS 35360 B -> 4 blocks/CU.
// ---------------------------------------------------------------------------
__global__ __launch_bounds__(256, 4) void conv3_mfma(
    const bf16* __restrict__ inp, const bf16* __restrict__ W3p,
    const float* __restrict__ xin, float* __restrict__ outp,
    const float* __restrict__ g3, const float* __restrict__ b3,
    const float* __restrict__ m3, const float* __restrict__ v3)
{
    __shared__ u16 sW[64*136];                 // 17408 B (one 64-co tap tile)
    __shared__ u16 sXh[66*136];                // 17952 B (halo strip)
    const int tid  = threadIdx.x;
    const int bid  = blockIdx.x;
    const int half = (bid >= 1152) ? 1 : 0;
    const int P0   = (bid - half*1152) * 64;
    const int co0  = half * 64;
    const int n    = P0 / HWS;
    const int hwb  = P0 - n*HWS;
    const int h = hwb / WW, wb = hwb - h*WW;   // 64-pix tile within one row
    const int lane = tid & 63, ln = lane & 15, g = lane >> 4;
    const int w = tid >> 6;                    // wave id -> m-tile (16 co)

    const int se  = tid;
    f32x4 acc[4];
    #pragma unroll
    for (int ni=0;ni<4;ni++) acc[ni] = (f32x4){0.f,0.f,0.f,0.f};

    for (int a = 0; a < 3; ++a){
        const int hs = h + 1 - a;              // source row for taps a*3+b
        if (hs < 0 || hs >= HH) continue;      // uniform per block
        const int tap0 = a*3;
        __syncthreads();                       // prior sW/strip reads done
        // stage halo strip: 66 cols (src col wb-1+cs) x 128 ch
        #pragma unroll
        for (int r = 0; r < 5; ++r){
            int e = se + r*256;
            if (e < 1056){
                int cs = e >> 4, grp = e & 15;
                int col = wb - 1 + cs;
                uint4 val = {0u,0u,0u,0u};
                if (col >= 0 && col < WW)
                    val = *(const uint4*)&inp[(size_t)(n*HWS + hs*WW + col)*CCH + grp*8];
                *(uint4*)&sXh[cs*136 + grp*8] = val;
            }
        }
        // stage W(tap0) directly to LDS
        #pragma unroll
        for (int r = 0; r < 4; ++r){
            int e = se + r*256; int row = e>>4, grp = e&15;
            *(uint4*)&sW[row*136 + grp*8] =
                *(const uint4*)&W3p[(size_t)tap0*16384 + (co0+row)*128 + grp*8];
        }
        __syncthreads();

        // prefetch W(tap0+1) into regs (hides L2 latency under MFMA b=0)
        uint4 wA[4];
        #pragma unroll
        for (int r = 0; r < 4; ++r){
            int e = se + r*256; int row = e>>4, grp = e&15;
            wA[r] = *(const uint4*)&W3p[(size_t)(tap0+1)*16384 + (co0+row)*128 + grp*8];
        }
        // MFMA b=0
        #pragma unroll
        for (int kk=0;kk<4;++kk){
            short8 fa = *(const short8*)&sW[(w*16+ln)*136 + kk*32 + g*8];
            #pragma unroll
            for (int ni=0;ni<4;++ni){
                short8 fb = *(const short8*)&sXh[(ni*16+ln+2)*136 + kk*32 + g*8];
                acc[ni] = __builtin_amdgcn_mfma_f32_16x16x32_bf16(fa, fb, acc[ni], 0, 0, 0);
            }
        }
        __syncthreads();                       // sW reads (b=0) done
        #pragma unroll
        for (int r = 0; r < 4; ++r){
            int e = se + r*256; int row = e>>4, grp = e&15;
            *(uint4*)&sW[row*136 + grp*8] = wA[r];
        }
        // prefetch W(tap0+2)
        uint4 wB[4];
        #pragma unroll
        for (int r = 0; r < 4; ++r){
            int e = se + r*256; int row = e>>4, grp = e&15;
            wB[r] = *(const uint4*)&W3p[(size_t)(tap0+2)*16384 + (co0+row)*128 + grp*8];
        }
        __syncthreads();                       // W(b=1) visible
        // MFMA b=1
        #pragma unroll
        for (int kk=0;kk<4;++kk){
            short8 fa = *(const short8*)&sW[(w*16+ln)*136 + kk*32 + g*8];
            #pragma unroll
            for (int ni=0;ni<4;++ni){
                short8 fb = *(const short8*)&sXh[(ni*16+ln+1)*136 + kk*32 + g*8];
                acc[ni] = __builtin_amdgcn_mfma_f32_16x16x32_bf16(fa, fb, acc[ni], 0, 0, 0);
            }
        }
        __syncthreads();                       // sW reads (b=1) done
        #pragma unroll
        for (int r = 0; r < 4; ++r){
            int e = se + r*256; int row = e>>4, grp = e&15;
            *(uint4*)&sW[row*136 + grp*8] = wB[r];
        }
        __syncthreads();                       // W(b=2) visible
        // MFMA b=2
        #pragma unroll
        for (int kk=0;kk<4;++kk){
            short8 fa = *(const short8*)&sW[(w*16+ln)*136 + kk*32 + g*8];
            #pragma unroll
            for (int ni=0;ni<4;++ni){
                short8 fb = *(const short8*)&sXh[(ni*16+ln)*136 + kk*32 + g*8];
                acc[ni] = __builtin_amdgcn_mfma_f32_16x16x32_bf16(fa, fb, acc[ni], 0, 0, 0);
            }
        }
    }

    #pragma unroll
    for (int j=0;j<4;++j){
        int co = co0 + w*16 + g*4 + j;
        float sg = g3[co]*rsqrtf(v3[co]+EPSV);
        float bc = b3[co] - m3[co]*sg;
        #pragma unroll
        for (int ni=0;ni<4;++ni){
            int pixl = hwb + ni*16 + ln;
            size_t idx = (size_t)(n*CCH + co)*HWS + pixl;
            float v = acc[ni][j]*sg + bc + xin[idx];
            outp[idx] = fmaxf(v, 0.f);
        }
    }
}

// ---------------------------------------------------------------------------
// MFMA halo attention v6 (r11-verified). 512 thr = 8 waves; 3 blocks/CU;
// T14 async V-stage; two-phase PV; direct-global Q/rel frags. No min-blocks.
// ---------------------------------------------------------------------------
__global__ __launch_bounds__(512) void attn_kernel(
    const u16* __restrict__ QK, const u16* __restrict__ vT,
    const u16* __restrict__ relb, bf16* __restrict__ outp)
{
    __shared__ __align__(16) char smem[46848];
    u16*   sK   = (u16*)(smem);
    u16*   sP   = (u16*)(smem);
    u16*   sVT  = (u16*)(smem + 20480);
    float* tT   = (float*)(smem + 37376);
    float* wredM= (float*)(smem + 45824);
    float* wredS= (float*)(smem + 46336);

    const int tid  = threadIdx.x;
    const int bid0 = blockIdx.x;
    const int bid  = (bid0 & 7) * 576 + (bid0 >> 3);   // XCD-contiguous chunks
    const int head = bid & 3;
    const int t    = bid >> 2;
    const int n    = t / NBLKS;
    const int blk  = t - n*NBLKS;
    const int bi = blk / 24, bj = blk - bi*24;
    const int row0 = bi*8 - 4, col0 = bj*8 - 4;
    const int ch0 = head*32;
    const int wv = tid >> 6, lane = tid & 63, ln = lane & 15, g = lane >> 4;
    const int nt = wv & 3, mh = wv >> 2;

    uint2 vreg[4];
    #pragma unroll
    for (int r = 0; r < 4; ++r){
        int e = tid + r*512;
        int d   = e >> 6;
        int rem = e & 63;
        int iw  = rem >> 2;
        int jc  = (rem & 3) * 4;
        int rr  = row0 + iw, cc0 = col0 + jc;
        uint2 vv = {0u,0u};
        if (rr >= 0 && rr < HH && cc0 >= 0 && cc0 < 189)
            vv = *(const uint2*)&vT[(size_t)(n*CCH + ch0 + d)*HWS + rr*WW + cc0];
        vreg[r] = vv;
    }

    #pragma unroll
    for (int r = 0; r < 2; ++r){
        int e = tid + r*512;                   // 0..1023
        int wp = e >> 2, q4 = e & 3;
        int rr = row0 + (wp>>4), cc2 = col0 + (wp&15);
        uint4 kk4 = {0u,0u,0u,0u};
        if (rr>=0 && rr<HH && cc2>=0 && cc2<WW){
            size_t P = (size_t)n*HWS + rr*WW + cc2;
            kk4 = *(const uint4*)&QK[P*256 + 128 + ch0 + q4*8];
        }
        *(uint4*)&sK[wp*40 + q4*8] = kk4;
    }

    const int qc = nt*16 + ln;
    size_t Pq = (size_t)n*HWS + (bi*8 + (qc>>3))*WW + bj*8 + (qc&7);
    const short8 qfrag = *(const short8*)&QK[Pq*256 + ch0 + g*8];
    __syncthreads();                                  // (1) K staged

    f32x4 accs[8];
    #pragma unroll
    for (int i=0;i<8;i++){
        short8 fk = *(const short8*)&sK[((mh*8+i)*16+ln)*40 + g*8];
        accs[i] = __builtin_amdgcn_mfma_f32_16x16x32_bf16(fk, qfrag, (f32x4){0.f,0.f,0.f,0.f}, 0, 0, 0);
    }

    {
        const u16* relX = relb + (mh ? 1024 : 0);
        #pragma unroll
        for (int ntr=0; ntr<2; ++ntr){
            short8 fr = *(const short8*)&relX[(ntr*16+ln)*32 + g*8];
            f32x4 L = __builtin_amdgcn_mfma_f32_16x16x32_bf16(qfrag, fr, (f32x4){0.f,0.f,0.f,0.f}, 0, 0, 0);
            #pragma unroll
            for (int r2=0;r2<4;r2++){
                int q  = nt*16 + g*4 + r2;
                int rr = ntr*16 + ln;
                int bq = mh ? (q&7) : (q>>3);
                int iw = rr - 15 + bq;
                if (iw >= 0 && iw < 16) tT[mh*1056 + iw*66 + q] = L[r2];
            }
        }
    }
    __syncthreads();                                  // (2) tT ready; sK dead

    float tw[4];
    bool cok[4];
    #pragma unroll
    for (int r2=0;r2<4;r2++){
        tw[r2] = tT[1056 + (g*4+r2)*66 + qc];
        int cc2 = col0 + g*4 + r2;
        cok[r2] = (cc2 >= 0 && cc2 < WW);
    }
    float mx = -3.4e38f;
    #pragma unroll
    for (int i=0;i<8;i++){
        int mt = mh*8 + i;
        int rr = row0 + mt;
        bool rok = (rr >= 0 && rr < HH);
        float th = tT[mt*66 + qc];
        #pragma unroll
        for (int r2=0;r2<4;r2++){
            float s = (rok && cok[r2]) ? (accs[i][r2] + th + tw[r2]) : -3.0e38f;
            accs[i][r2] = s;
            mx = fmaxf(mx, s);
        }
    }
    mx = fmaxf(mx, __shfl_xor(mx, 16));
    mx = fmaxf(mx, __shfl_xor(mx, 32));
    if (g == 0) wredM[mh*64 + qc] = mx;
    __syncthreads();                                  // (3) wredM ready

    #pragma unroll
    for (int r = 0; r < 4; ++r){
        int e = tid + r*512;
        int d   = e >> 6;
        int rem = e & 63;
        int iw  = rem >> 2;
        int jc  = (rem & 3) * 4;
        *(uint2*)&sVT[d*264 + iw*16 + jc] = vreg[r];
    }
    mx = fmaxf(wredM[qc], wredM[64 + qc]);

    float sm = 0.f;
    #pragma unroll
    for (int i=0;i<8;i++){
        #pragma unroll
        for (int r2=0;r2<4;r2++){
            float p = __expf(accs[i][r2] - mx);
            accs[i][r2] = p;
            sm += p;
        }
    }
    sm += __shfl_xor(sm, 16);
    sm += __shfl_xor(sm, 32);
    if (g == 0) wredS[mh*64 + qc] = sm;
    if (mh == 0){
        #pragma unroll
        for (int i=0;i<8;i++){
            u32* dst = (u32*)&sP[qc*136 + i*16 + g*4];
            dst[0] = pck(accs[i][0], accs[i][1]);
            dst[1] = pck(accs[i][2], accs[i][3]);
        }
    }
    __syncthreads();                                  // (4) P-A + wredS + sVT ready

    const int dt = wv & 1, qt = wv >> 1;
    f32x4 acco = (f32x4){0.f,0.f,0.f,0.f};
    #pragma unroll
    for (int ks=0; ks<4; ++ks){
        short8 fa = *(const short8*)&sVT[(dt*16+ln)*264 + ks*32 + g*8];
        short8 fb = *(const short8*)&sP [(qt*16+ln)*136 + ks*32 + g*8];
        acco = __builtin_amdgcn_mfma_f32_16x16x32_bf16(fa, fb, acco, 0, 0, 0);
    }
    __syncthreads();                                  // (5) P-A consumed
    if (mh == 1){
        #pragma unroll
        for (int i=0;i<8;i++){
            u32* dst = (u32*)&sP[qc*136 + i*16 + g*4];
            dst[0] = pck(accs[i][0], accs[i][1]);
            dst[1] = pck(accs[i][2], accs[i][3]);
        }
    }
    __syncthreads();                                  // (6) P-B ready

    #pragma unroll
    for (int ks=0; ks<4; ++ks){
        short8 fa = *(const short8*)&sVT[(dt*16+ln)*264 + 128 + ks*32 + g*8];
        short8 fb = *(const short8*)&sP [(qt*16+ln)*136 + ks*32 + g*8];
        acco = __builtin_amdgcn_mfma_f32_16x16x32_bf16(fa, fb, acco, 0, 0, 0);
    }
    {
        const int q = qt*16 + ln;
        const float inv = 1.f / (wredS[q] + wredS[64 + q]);
        size_t P = (size_t)n*HWS + (bi*8 + (q>>3))*WW + bj*8 + (q&7);
        uint2 ov;
        ov.x = pck(acco[0]*inv, acco[1]*inv);
        ov.y = pck(acco[2]*inv, acco[3]*inv);
        *(uint2*)&outp[P*CCH + ch0 + dt*16 + g*4] = ov;
    }
}

// ---------------------------------------------------------------------------
extern "C" void kernel_launch(void* const* d_in, const int* in_sizes, int n_in,
                              void* d_out, int out_size, void* d_ws, size_t ws_size,
                              hipStream_t stream)
{
    (void)in_sizes; (void)n_in; (void)out_size; (void)ws_size;
    const float* x      = (const float*)d_in[0];
    const float* w1     = (const float*)d_in[1];
    const float* bn1_g  = (const float*)d_in[2];
    const float* bn1_b  = (const float*)d_in[3];
    const float* bn1_m  = (const float*)d_in[4];
    const float* bn1_v  = (const float*)d_in[5];
    const float* to_q   = (const float*)d_in[6];
    const float* to_kv  = (const float*)d_in[7];
    const float* to_ow  = (const float*)d_in[8];
    const float* to_ob  = (const float*)d_in[9];
    const float* rel_h  = (const float*)d_in[10];
    const float* rel_w  = (const float*)d_in[11];
    const float* w3     = (const float*)d_in[12];
    const float* bn3_g  = (const float*)d_in[13];
    const float* bn3_b  = (const float*)d_in[14];
    const float* bn3_m  = (const float*)d_in[15];
    const float* bn3_v  = (const float*)d_in[16];

    char* ws   = (char*)d_ws;
    bf16* out1 = (bf16*)(ws + 0);              // [P][128]; later reused as out2
    bf16* qk   = (bf16*)(ws + 18874368);       // [P][256]  q|k
    bf16* vT   = (bf16*)(ws + 75497472);       // NCHW [n][128][HW]
    bf16* wb   = (bf16*)(ws + 94371840);       // weight blob + padded rel (462848 B)
    bf16* W3p  = wb + 81920;
    u16*  relb = (u16*)(wb + 229376);
    bf16* attnout = (bf16*)d_out;              // d_out as scratch until conv3
    bf16* out2    = out1;

    prep_w<<<904, 256, 0, stream>>>(w1, to_q, to_kv, to_ow, w3, rel_h, rel_w, wb);

    // conv1 (1x1) + BN1 + ReLU, fused NCHW->[P][128] transpose
    conv1_mfma<<<1152, 256, 0, stream>>>(x, wb, out1, bn1_g, bn1_b, bn1_m, bn1_v);
    // fused q|k|v: slabs 0,1 -> qk [P][256]; slab 2 -> vT NCHW (transposed epilogue)
    gemm_mfma<false,false,true><<<dim3(1152,3), 256, 0, stream>>>(
        out1, wb + 16384, qk, vT, 256, 0, nullptr);

    attn_kernel<<<4608, 512, 0, stream>>>((const u16*)qk, (const u16*)vT,
                                          relb, attnout);

    // out projection + bias + ReLU
    gemm_mfma<true,true,false><<<dim3(1152,1), 256, 0, stream>>>(
        attnout, wb + 65536, out2, nullptr, 128, 0, to_ob);

    // conv3 v4 (3x3 convT) + BN3 + residual + ReLU -> NCHW f32 d_out
    conv3_mfma<<<2304, 256, 0, stream>>>(out2, W3p, x, (float*)d_out,
                                         bn3_g, bn3_b, bn3_m, bn3_v);
}

// Round 15
// 156.232 us; speedup vs baseline: 1.2560x; 1.2560x over previous
//
#include <hip/hip_runtime.h>
#include <hip/hip_bf16.h>

using bf16 = __hip_bfloat16;
typedef unsigned short u16;
typedef unsigned int   u32;
typedef __attribute__((ext_vector_type(8))) short short8;   // 8 bf16 = 4 VGPRs (MFMA A/B frag)
typedef __attribute__((ext_vector_type(4))) float f32x4;    // MFMA C/D frag

#define B_N 2
#define CCH 128
#define HH 192
#define WW 192
#define HWS (HH*WW)          // 36864
#define NBLKS 576            // 24*24 halo blocks per batch
#define EPSV 1e-5f
#define LDW 136              // LDS row stride (u16) for MFMA tiles

__device__ __forceinline__ float b2f(bf16 v){ return __bfloat162float(v); }
__device__ __forceinline__ bf16  f2b(float v){ return __float2bfloat16(v); }
__device__ __forceinline__ u32 pck(float a, float b){
    bf16 x = f2b(a), y = f2b(b);
    return (u32)*(u16*)&x | ((u32)*(u16*)&y << 16);
}

// ---------------------------------------------------------------------------
// Weight prep -> bf16 blob, all [co][ci]:
// [0,16K) W1 | [16K,32K) Wq*qscale | [32K,48K) Wk | [48K,64K) Wv | [64K,80K) Wo
// [80K,224K) W3 [tap][co][ci] | [229376,230400) rel_h (992+32 zero pad)
// [230400,231424) rel_w (992+32 zero pad)
// ---------------------------------------------------------------------------
__global__ __launch_bounds__(256) void prep_w(
    const float* __restrict__ w1, const float* __restrict__ to_q,
    const float* __restrict__ to_kv, const float* __restrict__ to_ow,
    const float* __restrict__ w3, const float* __restrict__ relh,
    const float* __restrict__ relw, bf16* __restrict__ wb)
{
    int i = blockIdx.x*256 + threadIdx.x;      // < 231424 (904*256)
    float v;
    if (i < 16384){       int co=(i>>7)&127, ci=i&127;      v = w1[ci*128+co]; }
    else if (i < 32768){  int r=i-16384; int co=r>>7, ci=r&127; v = to_q[ci*128+co]*0.17677669529663687f; }
    else if (i < 49152){  int r=i-32768; int co=r>>7, ci=r&127; v = to_kv[ci*256+co]; }
    else if (i < 65536){  int r=i-49152; int co=r>>7, ci=r&127; v = to_kv[ci*256+128+co]; }
    else if (i < 81920){  int r=i-65536; int co=r>>7, ci=r&127; v = to_ow[ci*128+co]; }
    else if (i < 229376){ int r=i-81920; int tap=r>>14, co=(r>>7)&127, ci=r&127; int a=tap/3, b=tap-a*3;
                          v = w3[((size_t)(ci*128+co)*3+a)*3+b]; }
    else if (i < 230400){ int j=i-229376; v = (j < 992) ? relh[j] : 0.f; }
    else                { int j=i-230400; v = (j < 992) ? relw[j] : 0.f; }
    wb[i] = f2b(v);
}

// ---------------------------------------------------------------------------
// conv1: NCHW f32 input -> fused LDS transpose -> MFMA -> BN1+ReLU -> [P][128]
// ---------------------------------------------------------------------------
__global__ __launch_bounds__(256) void conv1_mfma(
    const float* __restrict__ x, const bf16* __restrict__ Wp,
    bf16* __restrict__ outp,
    const float* __restrict__ bn_g, const float* __restrict__ bn_b,
    const float* __restrict__ bn_m, const float* __restrict__ bn_v)
{
    __shared__ float tF[128*68];               // 34816 B; sW overlays after pack
    __shared__ u16   sX[64*LDW];               // 17408 B
    u16* sW = (u16*)tF;
    const int tid  = threadIdx.x;
    const int pix0 = blockIdx.x * 64;
    const int n    = pix0 / HWS;
    const int hwb  = pix0 - n*HWS;
    const int lane = tid & 63;
    const int ln = lane & 15, g = lane >> 4;
    const int cow = (tid >> 6) * 32;

    #pragma unroll
    for (int r = 0; r < 8; ++r){
        int e = tid + r*256;                   // 0..2047
        int ci = e >> 4, p4 = e & 15;
        *(float4*)&tF[ci*68 + p4*4] =
            *(const float4*)&x[(size_t)(n*CCH + ci)*HWS + hwb + p4*4];
    }
    __syncthreads();
    {
        const int pix = tid & 63, cq = tid >> 6;
        u32 pkt[16];
        #pragma unroll
        for (int c = 0; c < 16; ++c){
            int ci = cq*32 + c*2;
            pkt[c] = pck(tF[ci*68 + pix], tF[(ci+1)*68 + pix]);
        }
        u32* dst = (u32*)&sX[pix*LDW + cq*32];
        #pragma unroll
        for (int c = 0; c < 16; ++c) dst[c] = pkt[c];
    }
    __syncthreads();
    #pragma unroll
    for (int r = 0; r < 8; ++r){
        int e = tid + r*256; int row = e>>4, grp = e&15;
        *(uint4*)&sW[row*LDW + grp*8] = *(const uint4*)&Wp[row*128 + grp*8];
    }
    __syncthreads();

    f32x4 acc[4][2];
    #pragma unroll
    for (int mi=0;mi<4;mi++)
        #pragma unroll
        for (int ni=0;ni<2;ni++) acc[mi][ni] = (f32x4){0.f,0.f,0.f,0.f};
    #pragma unroll
    for (int kk = 0; kk < 4; ++kk){
        short8 fa[4], fb[2];
        #pragma unroll
        for (int mi=0;mi<4;mi++)
            fa[mi] = *(const short8*)&sX[(mi*16+ln)*LDW + kk*32 + g*8];
        #pragma unroll
        for (int ni=0;ni<2;ni++)
            fb[ni] = *(const short8*)&sW[(cow+ni*16+ln)*LDW + kk*32 + g*8];
        #pragma unroll
        for (int mi=0;mi<4;mi++)
            #pragma unroll
            for (int ni=0;ni<2;ni++)
                acc[mi][ni] = __builtin_amdgcn_mfma_f32_16x16x32_bf16(fa[mi], fb[ni], acc[mi][ni], 0, 0, 0);
    }
    float sc[2], bb[2];
    #pragma unroll
    for (int ni=0;ni<2;ni++){
        int co = cow + ni*16 + ln;
        float sg = bn_g[co]*rsqrtf(bn_v[co]+EPSV);
        sc[ni] = sg; bb[ni] = bn_b[co] - bn_m[co]*sg;
    }
    #pragma unroll
    for (int mi=0;mi<4;mi++)
        #pragma unroll
        for (int ni=0;ni<2;ni++)
            #pragma unroll
            for (int j=0;j<4;j++){
                int pix = pix0 + mi*16 + g*4 + j;
                int co  = cow + ni*16 + ln;
                float v = fmaxf(acc[mi][ni][j]*sc[ni] + bb[ni], 0.f);
                outp[(size_t)pix*CCH + co] = f2b(v);
            }
}

// ---------------------------------------------------------------------------
// MFMA channel GEMM (verified r5-r14). blockIdx.y selects a 128-co slab.
// TRANS_Y2: slab y==2 writes output transposed NCHW to outp2 (for V).
// ---------------------------------------------------------------------------
template<bool DO_BIAS, bool DO_RELU, bool TRANS_Y2>
__global__ __launch_bounds__(256) void gemm_mfma(
    const bf16* __restrict__ inp, const bf16* __restrict__ Wp,
    bf16* __restrict__ outp, bf16* __restrict__ outp2, int cstride, int choff,
    const float* __restrict__ bias)
{
    Wp    += (size_t)blockIdx.y * 16384;
    choff += blockIdx.y * 128;
    __shared__ u16 sW[128*LDW];
    __shared__ u16 sX[64*LDW];
    const int tid  = threadIdx.x;
    const int pix0 = blockIdx.x * 64;
    const int lane = tid & 63;
    const int ln = lane & 15, g = lane >> 4;
    const int cow = (tid >> 6) * 32;

    #pragma unroll
    for (int r = 0; r < 8; ++r){
        int e = tid + r*256; int row = e>>4, grp = e&15;
        *(uint4*)&sW[row*LDW + grp*8] = *(const uint4*)&Wp[row*128 + grp*8];
    }
    #pragma unroll
    for (int r = 0; r < 4; ++r){
        int e = tid + r*256; int row = e>>4, grp = e&15;
        *(uint4*)&sX[row*LDW + grp*8] = *(const uint4*)&inp[(size_t)(pix0+row)*CCH + grp*8];
    }
    __syncthreads();

    f32x4 acc[4][2];
    #pragma unroll
    for (int mi=0;mi<4;mi++)
        #pragma unroll
        for (int ni=0;ni<2;ni++) acc[mi][ni] = (f32x4){0.f,0.f,0.f,0.f};

    #pragma unroll
    for (int kk = 0; kk < 4; ++kk){
        short8 fa[4], fb[2];
        #pragma unroll
        for (int mi=0;mi<4;mi++)
            fa[mi] = *(const short8*)&sX[(mi*16+ln)*LDW + kk*32 + g*8];
        #pragma unroll
        for (int ni=0;ni<2;ni++)
            fb[ni] = *(const short8*)&sW[(cow+ni*16+ln)*LDW + kk*32 + g*8];
        #pragma unroll
        for (int mi=0;mi<4;mi++)
            #pragma unroll
            for (int ni=0;ni<2;ni++)
                acc[mi][ni] = __builtin_amdgcn_mfma_f32_16x16x32_bf16(fa[mi], fb[ni], acc[mi][ni], 0, 0, 0);
    }

    if (TRANS_Y2 && blockIdx.y == 2){
        __syncthreads();
        u16* tile = sX;
        #pragma unroll
        for (int mi=0;mi<4;mi++)
            #pragma unroll
            for (int ni=0;ni<2;ni++){
                int co   = cow + ni*16 + ln;
                int pixl = mi*16 + g*4;
                *(u32*)&tile[co*68 + pixl]     = pck(acc[mi][ni][0], acc[mi][ni][1]);
                *(u32*)&tile[co*68 + pixl + 2] = pck(acc[mi][ni][2], acc[mi][ni][3]);
            }
        __syncthreads();
        const int co2 = tid >> 1, hf = tid & 1;
        const int n2 = pix0 / HWS, hwb2 = pix0 - n2*HWS;
        u16* gdst = (u16*)outp2 + (size_t)(n2*CCH + co2)*HWS + hwb2 + hf*32;
        const u16* src = &tile[co2*68 + hf*32];
        #pragma unroll
        for (int k=0;k<8;k++)
            *(uint2*)&gdst[k*4] = *(const uint2*)&src[k*4];
        return;
    }

    float bb[2];
    #pragma unroll
    for (int ni=0;ni<2;ni++){
        int co = cow + ni*16 + ln;
        bb[ni] = DO_BIAS ? bias[co] : 0.f;
    }
    #pragma unroll
    for (int mi=0;mi<4;mi++)
        #pragma unroll
        for (int ni=0;ni<2;ni++)
            #pragma unroll
            for (int j=0;j<4;j++){
                int pix = pix0 + mi*16 + g*4 + j;
                int co  = cow + ni*16 + ln;
                float v = acc[mi][ni][j] + bb[ni];
                if (DO_RELU) v = fmaxf(v, 0.f);
                outp[(size_t)pix*cstride + choff + co] = f2b(v);
            }
}

// ---------------------------------------------------------------------------
// conv3 v5 = r13/r14 structure MINUS the reg-prefetch (the prefetch registers
// were the spill source: VGPR capped at 56, 253 MB scratch writes measured in
// r13/r14). W(tap) staged straight into LDS between barriers; live state ~45
// VGPRs -> no spill at any occupancy. X halo strip serves 3 column taps
// (verified r12-r14); 64-co split with same-XCD pairing (bid>=1152).
// LDS 35360 B -> 4 blocks/CU.
// ---------------------------------------------------------------------------
__global__ __launch_bounds__(256) void conv3_mfma(
    const bf16* __restrict__ inp, const bf16* __restrict__ W3p,
    const float* __restrict__ xin, float* __restrict__ outp,
    const float* __restrict__ g3, const float* __restrict__ b3,
    const float* __restrict__ m3, const float* __restrict__ v3)
{
    __shared__ u16 sW[64*136];                 // 17408 B (one 64-co tap tile)
    __shared__ u16 sXh[66*136];                // 17952 B (halo strip)
    const int tid  = threadIdx.x;
    const int bid  = blockIdx.x;
    const int half = (bid >= 1152) ? 1 : 0;
    const int P0   = (bid - half*1152) * 64;
    const int co0  = half * 64;
    const int n    = P0 / HWS;
    const int hwb  = P0 - n*HWS;
    const int h = hwb / WW, wb = hwb - h*WW;   // 64-pix tile within one row
    const int lane = tid & 63, ln = lane & 15, g = lane >> 4;
    const int w = tid >> 6;                    // wave id -> m-tile (16 co)

    f32x4 acc[4];
    #pragma unroll
    for (int ni=0;ni<4;ni++) acc[ni] = (f32x4){0.f,0.f,0.f,0.f};

    for (int a = 0; a < 3; ++a){
        const int hs = h + 1 - a;              // source row for taps a*3+b
        if (hs < 0 || hs >= HH) continue;      // uniform per block
        const int tap0 = a*3;
        __syncthreads();                       // prior sW/strip reads done
        // stage halo strip: 66 cols (src col wb-1+cs) x 128 ch
        #pragma unroll
        for (int r = 0; r < 5; ++r){
            int e = tid + r*256;
            if (e < 1056){
                int cs = e >> 4, grp = e & 15;
                int col = wb - 1 + cs;
                uint4 val = {0u,0u,0u,0u};
                if (col >= 0 && col < WW)
                    val = *(const uint4*)&inp[(size_t)(n*HWS + hs*WW + col)*CCH + grp*8];
                *(uint4*)&sXh[cs*136 + grp*8] = val;
            }
        }
        // stage W(tap0)
        #pragma unroll
        for (int r = 0; r < 4; ++r){
            int e = tid + r*256; int row = e>>4, grp = e&15;
            *(uint4*)&sW[row*136 + grp*8] =
                *(const uint4*)&W3p[(size_t)tap0*16384 + (co0+row)*128 + grp*8];
        }
        __syncthreads();
        // MFMA b=0 (column shift +2)
        #pragma unroll
        for (int kk=0;kk<4;++kk){
            short8 fa = *(const short8*)&sW[(w*16+ln)*136 + kk*32 + g*8];
            #pragma unroll
            for (int ni=0;ni<4;++ni){
                short8 fb = *(const short8*)&sXh[(ni*16+ln+2)*136 + kk*32 + g*8];
                acc[ni] = __builtin_amdgcn_mfma_f32_16x16x32_bf16(fa, fb, acc[ni], 0, 0, 0);
            }
        }
        __syncthreads();                       // sW reads (b=0) done
        // stage W(tap0+1)
        #pragma unroll
        for (int r = 0; r < 4; ++r){
            int e = tid + r*256; int row = e>>4, grp = e&15;
            *(uint4*)&sW[row*136 + grp*8] =
                *(const uint4*)&W3p[(size_t)(tap0+1)*16384 + (co0+row)*128 + grp*8];
        }
        __syncthreads();                       // W(b=1) visible
        // MFMA b=1 (column shift +1)
        #pragma unroll
        for (int kk=0;kk<4;++kk){
            short8 fa = *(const short8*)&sW[(w*16+ln)*136 + kk*32 + g*8];
            #pragma unroll
            for (int ni=0;ni<4;++ni){
                short8 fb = *(const short8*)&sXh[(ni*16+ln+1)*136 + kk*32 + g*8];
                acc[ni] = __builtin_amdgcn_mfma_f32_16x16x32_bf16(fa, fb, acc[ni], 0, 0, 0);
            }
        }
        __syncthreads();                       // sW reads (b=1) done
        // stage W(tap0+2)
        #pragma unroll
        for (int r = 0; r < 4; ++r){
            int e = tid + r*256; int row = e>>4, grp = e&15;
            *(uint4*)&sW[row*136 + grp*8] =
                *(const uint4*)&W3p[(size_t)(tap0+2)*16384 + (co0+row)*128 + grp*8];
        }
        __syncthreads();                       // W(b=2) visible
        // MFMA b=2 (column shift 0)
        #pragma unroll
        for (int kk=0;kk<4;++kk){
            short8 fa = *(const short8*)&sW[(w*16+ln)*136 + kk*32 + g*8];
            #pragma unroll
            for (int ni=0;ni<4;++ni){
                short8 fb = *(const short8*)&sXh[(ni*16+ln)*136 + kk*32 + g*8];
                acc[ni] = __builtin_amdgcn_mfma_f32_16x16x32_bf16(fa, fb, acc[ni], 0, 0, 0);
            }
        }
    }

    #pragma unroll
    for (int j=0;j<4;++j){
        int co = co0 + w*16 + g*4 + j;
        float sg = g3[co]*rsqrtf(v3[co]+EPSV);
        float bc = b3[co] - m3[co]*sg;
        #pragma unroll
        for (int ni=0;ni<4;++ni){
            int pixl = hwb + ni*16 + ln;
            size_t idx = (size_t)(n*CCH + co)*HWS + pixl;
            float v = acc[ni][j]*sg + bc + xin[idx];
            outp[idx] = fmaxf(v, 0.f);
        }
    }
}

// ---------------------------------------------------------------------------
// MFMA halo attention v6 (r11-verified). 512 thr = 8 waves; 3 blocks/CU;
// T14 async V-stage; two-phase PV; direct-global Q/rel frags. No min-blocks.
// ---------------------------------------------------------------------------
__global__ __launch_bounds__(512) void attn_kernel(
    const u16* __restrict__ QK, const u16* __restrict__ vT,
    const u16* __restrict__ relb, bf16* __restrict__ outp)
{
    __shared__ __align__(16) char smem[46848];
    u16*   sK   = (u16*)(smem);
    u16*   sP   = (u16*)(smem);
    u16*   sVT  = (u16*)(smem + 20480);
    float* tT   = (float*)(smem + 37376);
    float* wredM= (float*)(smem + 45824);
    float* wredS= (float*)(smem + 46336);

    const int tid  = threadIdx.x;
    const int bid0 = blockIdx.x;
    const int bid  = (bid0 & 7) * 576 + (bid0 >> 3);   // XCD-contiguous chunks
    const int head = bid & 3;
    const int t    = bid >> 2;
    const int n    = t / NBLKS;
    const int blk  = t - n*NBLKS;
    const int bi = blk / 24, bj = blk - bi*24;
    const int row0 = bi*8 - 4, col0 = bj*8 - 4;
    const int ch0 = head*32;
    const int wv = tid >> 6, lane = tid & 63, ln = lane & 15, g = lane >> 4;
    const int nt = wv & 3, mh = wv >> 2;

    uint2 vreg[4];
    #pragma unroll
    for (int r = 0; r < 4; ++r){
        int e = tid + r*512;
        int d   = e >> 6;
        int rem = e & 63;
        int iw  = rem >> 2;
        int jc  = (rem & 3) * 4;
        int rr  = row0 + iw, cc0 = col0 + jc;
        uint2 vv = {0u,0u};
        if (rr >= 0 && rr < HH && cc0 >= 0 && cc0 < 189)
            vv = *(const uint2*)&vT[(size_t)(n*CCH + ch0 + d)*HWS + rr*WW + cc0];
        vreg[r] = vv;
    }

    #pragma unroll
    for (int r = 0; r < 2; ++r){
        int e = tid + r*512;                   // 0..1023
        int wp = e >> 2, q4 = e & 3;
        int rr = row0 + (wp>>4), cc2 = col0 + (wp&15);
        uint4 kk4 = {0u,0u,0u,0u};
        if (rr>=0 && rr<HH && cc2>=0 && cc2<WW){
            size_t P = (size_t)n*HWS + rr*WW + cc2;
            kk4 = *(const uint4*)&QK[P*256 + 128 + ch0 + q4*8];
        }
        *(uint4*)&sK[wp*40 + q4*8] = kk4;
    }

    const int qc = nt*16 + ln;
    size_t Pq = (size_t)n*HWS + (bi*8 + (qc>>3))*WW + bj*8 + (qc&7);
    const short8 qfrag = *(const short8*)&QK[Pq*256 + ch0 + g*8];
    __syncthreads();                                  // (1) K staged

    f32x4 accs[8];
    #pragma unroll
    for (int i=0;i<8;i++){
        short8 fk = *(const short8*)&sK[((mh*8+i)*16+ln)*40 + g*8];
        accs[i] = __builtin_amdgcn_mfma_f32_16x16x32_bf16(fk, qfrag, (f32x4){0.f,0.f,0.f,0.f}, 0, 0, 0);
    }

    {
        const u16* relX = relb + (mh ? 1024 : 0);
        #pragma unroll
        for (int ntr=0; ntr<2; ++ntr){
            short8 fr = *(const short8*)&relX[(ntr*16+ln)*32 + g*8];
            f32x4 L = __builtin_amdgcn_mfma_f32_16x16x32_bf16(qfrag, fr, (f32x4){0.f,0.f,0.f,0.f}, 0, 0, 0);
            #pragma unroll
            for (int r2=0;r2<4;r2++){
                int q  = nt*16 + g*4 + r2;
                int rr = ntr*16 + ln;
                int bq = mh ? (q&7) : (q>>3);
                int iw = rr - 15 + bq;
                if (iw >= 0 && iw < 16) tT[mh*1056 + iw*66 + q] = L[r2];
            }
        }
    }
    __syncthreads();                                  // (2) tT ready; sK dead

    float tw[4];
    bool cok[4];
    #pragma unroll
    for (int r2=0;r2<4;r2++){
        tw[r2] = tT[1056 + (g*4+r2)*66 + qc];
        int cc2 = col0 + g*4 + r2;
        cok[r2] = (cc2 >= 0 && cc2 < WW);
    }
    float mx = -3.4e38f;
    #pragma unroll
    for (int i=0;i<8;i++){
        int mt = mh*8 + i;
        int rr = row0 + mt;
        bool rok = (rr >= 0 && rr < HH);
        float th = tT[mt*66 + qc];
        #pragma unroll
        for (int r2=0;r2<4;r2++){
            float s = (rok && cok[r2]) ? (accs[i][r2] + th + tw[r2]) : -3.0e38f;
            accs[i][r2] = s;
            mx = fmaxf(mx, s);
        }
    }
    mx = fmaxf(mx, __shfl_xor(mx, 16));
    mx = fmaxf(mx, __shfl_xor(mx, 32));
    if (g == 0) wredM[mh*64 + qc] = mx;
    __syncthreads();                                  // (3) wredM ready

    #pragma unroll
    for (int r = 0; r < 4; ++r){
        int e = tid + r*512;
        int d   = e >> 6;
        int rem = e & 63;
        int iw  = rem >> 2;
        int jc  = (rem & 3) * 4;
        *(uint2*)&sVT[d*264 + iw*16 + jc] = vreg[r];
    }
    mx = fmaxf(wredM[qc], wredM[64 + qc]);

    float sm = 0.f;
    #pragma unroll
    for (int i=0;i<8;i++){
        #pragma unroll
        for (int r2=0;r2<4;r2++){
            float p = __expf(accs[i][r2] - mx);
            accs[i][r2] = p;
            sm += p;
        }
    }
    sm += __shfl_xor(sm, 16);
    sm += __shfl_xor(sm, 32);
    if (g == 0) wredS[mh*64 + qc] = sm;
    if (mh == 0){
        #pragma unroll
        for (int i=0;i<8;i++){
            u32* dst = (u32*)&sP[qc*136 + i*16 + g*4];
            dst[0] = pck(accs[i][0], accs[i][1]);
            dst[1] = pck(accs[i][2], accs[i][3]);
        }
    }
    __syncthreads();                                  // (4) P-A + wredS + sVT ready

    const int dt = wv & 1, qt = wv >> 1;
    f32x4 acco = (f32x4){0.f,0.f,0.f,0.f};
    #pragma unroll
    for (int ks=0; ks<4; ++ks){
        short8 fa = *(const short8*)&sVT[(dt*16+ln)*264 + ks*32 + g*8];
        short8 fb = *(const short8*)&sP [(qt*16+ln)*136 + ks*32 + g*8];
        acco = __builtin_amdgcn_mfma_f32_16x16x32_bf16(fa, fb, acco, 0, 0, 0);
    }
    __syncthreads();                                  // (5) P-A consumed
    if (mh == 1){
        #pragma unroll
        for (int i=0;i<8;i++){
            u32* dst = (u32*)&sP[qc*136 + i*16 + g*4];
            dst[0] = pck(accs[i][0], accs[i][1]);
            dst[1] = pck(accs[i][2], accs[i][3]);
        }
    }
    __syncthreads();                                  // (6) P-B ready

    #pragma unroll
    for (int ks=0; ks<4; ++ks){
        short8 fa = *(const short8*)&sVT[(dt*16+ln)*264 + 128 + ks*32 + g*8];
        short8 fb = *(const short8*)&sP [(qt*16+ln)*136 + ks*32 + g*8];
        acco = __builtin_amdgcn_mfma_f32_16x16x32_bf16(fa, fb, acco, 0, 0, 0);
    }
    {
        const int q = qt*16 + ln;
        const float inv = 1.f / (wredS[q] + wredS[64 + q]);
        size_t P = (size_t)n*HWS + (bi*8 + (q>>3))*WW + bj*8 + (q&7);
        uint2 ov;
        ov.x = pck(acco[0]*inv, acco[1]*inv);
        ov.y = pck(acco[2]*inv, acco[3]*inv);
        *(uint2*)&outp[P*CCH + ch0 + dt*16 + g*4] = ov;
    }
}

// ---------------------------------------------------------------------------
extern "C" void kernel_launch(void* const* d_in, const int* in_sizes, int n_in,
                              void* d_out, int out_size, void* d_ws, size_t ws_size,
                              hipStream_t stream)
{
    (void)in_sizes; (void)n_in; (void)out_size; (void)ws_size;
    const float* x      = (const float*)d_in[0];
    const float* w1     = (const float*)d_in[1];
    const float* bn1_g  = (const float*)d_in[2];
    const float* bn1_b  = (const float*)d_in[3];
    const float* bn1_m  = (const float*)d_in[4];
    const float* bn1_v  = (const float*)d_in[5];
    const float* to_q   = (const float*)d_in[6];
    const float* to_kv  = (const float*)d_in[7];
    const float* to_ow  = (const float*)d_in[8];
    const float* to_ob  = (const float*)d_in[9];
    const float* rel_h  = (const float*)d_in[10];
    const float* rel_w  = (const float*)d_in[11];
    const float* w3     = (const float*)d_in[12];
    const float* bn3_g  = (const float*)d_in[13];
    const float* bn3_b  = (const float*)d_in[14];
    const float* bn3_m  = (const float*)d_in[15];
    const float* bn3_v  = (const float*)d_in[16];

    char* ws   = (char*)d_ws;
    bf16* out1 = (bf16*)(ws + 0);              // [P][128]; later reused as out2
    bf16* qk   = (bf16*)(ws + 18874368);       // [P][256]  q|k
    bf16* vT   = (bf16*)(ws + 75497472);       // NCHW [n][128][HW]
    bf16* wb   = (bf16*)(ws + 94371840);       // weight blob + padded rel (462848 B)
    bf16* W3p  = wb + 81920;
    u16*  relb = (u16*)(wb + 229376);
    bf16* attnout = (bf16*)d_out;              // d_out as scratch until conv3
    bf16* out2    = out1;

    prep_w<<<904, 256, 0, stream>>>(w1, to_q, to_kv, to_ow, w3, rel_h, rel_w, wb);

    // conv1 (1x1) + BN1 + ReLU, fused NCHW->[P][128] transpose
    conv1_mfma<<<1152, 256, 0, stream>>>(x, wb, out1, bn1_g, bn1_b, bn1_m, bn1_v);
    // fused q|k|v: slabs 0,1 -> qk [P][256]; slab 2 -> vT NCHW (transposed epilogue)
    gemm_mfma<false,false,true><<<dim3(1152,3), 256, 0, stream>>>(
        out1, wb + 16384, qk, vT, 256, 0, nullptr);

    attn_kernel<<<4608, 512, 0, stream>>>((const u16*)qk, (const u16*)vT,
                                          relb, attnout);

    // out projection + bias + ReLU
    gemm_mfma<true,true,false><<<dim3(1152,1), 256, 0, stream>>>(
        attnout, wb + 65536, out2, nullptr, 128, 0, to_ob);

    // conv3 v5 (3x3 convT) + BN3 + residual + ReLU -> NCHW f32 d_out
    conv3_mfma<<<2304, 256, 0, stream>>>(out2, W3p, x, (float*)d_out,
                                         bn3_g, bn3_b, bn3_m, bn3_v);
}